// Round 1
// baseline (305.777 us; speedup 1.0000x reference)
//
#include <hip/hip_runtime.h>
#include <stdint.h>

#define B_DIM 512
#define N_DIM 8192
#define D_DIM 1024
#define DA_DIM 512
#define S_DIM 8
#define DK_DIM 64
#define C_DIM 512   // S_DIM * DK_DIM

typedef short v8s __attribute__((ext_vector_type(8)));
typedef float v4f __attribute__((ext_vector_type(4)));

__device__ __forceinline__ unsigned int f2bf(float x) {
    union { float f; unsigned int u; } v; v.f = x;
    unsigned int u = v.u;
    return (u + 0x7fffu + ((u >> 16) & 1u)) >> 16;   // RNE f32 -> bf16
}

// ---------------- K0: pool f32 -> bf16 ----------------
__global__ __launch_bounds__(256) void cvt_pool(const float* __restrict__ src,
                                                unsigned short* __restrict__ dst) {
    int t = blockIdx.x * 256 + threadIdx.x;          // 0 .. 1048575, 8 floats each
    const float4* s4 = (const float4*)src;
    float4 a = s4[2 * t], b = s4[2 * t + 1];
    uint4 o;
    o.x = f2bf(a.x) | (f2bf(a.y) << 16);
    o.y = f2bf(a.z) | (f2bf(a.w) << 16);
    o.z = f2bf(b.x) | (f2bf(b.y) << 16);
    o.w = f2bf(b.z) | (f2bf(b.w) << 16);
    ((uint4*)dst)[t] = o;
}

// ---------------- K2: W_K [S][D][DK] -> Wt bf16 [C][D] ----------------
__global__ __launch_bounds__(256) void cvt_wk(const float* __restrict__ wk,
                                              unsigned short* __restrict__ wt) {
    int c = blockIdx.x;                               // 0..511
    int a = c >> 6, k = c & 63;
    const float* src = wk + (size_t)a * D_DIM * DK_DIM + k;
    unsigned short* drow = wt + (size_t)c * D_DIM;
    for (int d = threadIdx.x; d < D_DIM; d += 256)
        drow[d] = (unsigned short)f2bf(src[(size_t)d * DK_DIM]);
}

// ---------------- K1: queries -> normalize -> fold w -> Qw bf16 [B][C] ----------------
__global__ __launch_bounds__(256) void prep_q(const float* __restrict__ z,
                                              const float* __restrict__ wq,
                                              const float* __restrict__ logits,
                                              unsigned short* __restrict__ qwb) {
    __shared__ float zs[64 * 64];
    int a = blockIdx.x;          // aspect
    int b0 = blockIdx.y * 64;    // b base
    int tid = threadIdx.x;
    int k = tid & 63, bq = tid >> 6;

    // softmax over 8 logits (tiny, per-thread)
    float l[8]; float mx = -1e30f;
    #pragma unroll
    for (int i = 0; i < 8; i++) { l[i] = logits[i]; mx = fmaxf(mx, l[i]); }
    float se = 0.f;
    #pragma unroll
    for (int i = 0; i < 8; i++) { l[i] = __expf(l[i] - mx); se += l[i]; }
    float wa = l[a] / se;

    float acc[16];
    #pragma unroll
    for (int i = 0; i < 16; i++) acc[i] = 0.f;

    for (int dc = 0; dc < DA_DIM; dc += 64) {
        __syncthreads();
        #pragma unroll
        for (int j = 0; j < 4; j++) {
            int v = tid + 256 * j;               // float4 index 0..1023
            int row = v >> 4, ce = (v & 15) * 4; // element offset in chunk
            *(float4*)&zs[row * 64 + ce] =
                *(const float4*)&z[(size_t)(b0 + row) * DA_DIM + dc + ce];
        }
        __syncthreads();
        #pragma unroll 4
        for (int dl = 0; dl < 64; dl++) {
            float w = wq[((size_t)a * DA_DIM + dc + dl) * DK_DIM + k];
            #pragma unroll
            for (int i = 0; i < 16; i++)
                acc[i] = fmaf(zs[(bq * 16 + i) * 64 + dl], w, acc[i]);
        }
    }
    // normalize over k (across the 64 lanes), scale by wa, emit bf16
    for (int i = 0; i < 16; i++) {
        float ss = acc[i] * acc[i];
        for (int off = 32; off > 0; off >>= 1) ss += __shfl_xor(ss, off, 64);
        float sc = wa / (sqrtf(ss) + 1e-8f);
        int b = b0 + bq * 16 + i;
        qwb[(size_t)b * C_DIM + a * 64 + k] = (unsigned short)f2bf(acc[i] * sc);
    }
}

// ---------------- shared MFMA mainloop: C[128x128] = A[128xK] * B[128xK]^T ----------------
template <int KDIM>
__device__ __forceinline__ void gemm_mainloop(const unsigned short* __restrict__ A, int lda,
                                              const unsigned short* __restrict__ Bm, int ldb,
                                              int mbase, int nbase,
                                              unsigned short* As, unsigned short* Bs,
                                              v4f acc[4][4]) {
    int tid = threadIdx.x;
    int wid = tid >> 6, lane = tid & 63;
    int wm = wid >> 1, wn = wid & 1;
    int quad = lane >> 4, l16 = lane & 15;
    int srow = tid >> 2, scg = (tid & 3) * 8;

    for (int kk = 0; kk < KDIM / 32; kk++) {
        #pragma unroll
        for (int j = 0; j < 2; j++) {
            int row = srow + j * 64;
            *(uint4*)&As[row * 32 + scg] =
                *(const uint4*)&A[(size_t)(mbase + row) * lda + kk * 32 + scg];
            *(uint4*)&Bs[row * 32 + scg] =
                *(const uint4*)&Bm[(size_t)(nbase + row) * ldb + kk * 32 + scg];
        }
        __syncthreads();
        v8s af[4], bf[4];
        #pragma unroll
        for (int mt = 0; mt < 4; mt++)
            af[mt] = *(const v8s*)&As[(wm * 64 + mt * 16 + l16) * 32 + quad * 8];
        #pragma unroll
        for (int nt = 0; nt < 4; nt++)
            bf[nt] = *(const v8s*)&Bs[(wn * 64 + nt * 16 + l16) * 32 + quad * 8];
        #pragma unroll
        for (int mt = 0; mt < 4; mt++)
            #pragma unroll
            for (int nt = 0; nt < 4; nt++)
                acc[mt][nt] = __builtin_amdgcn_mfma_f32_16x16x32_bf16(
                    af[mt], bf[nt], acc[mt][nt], 0, 0, 0);
        __syncthreads();
    }
}

// ---------------- K3: keys = pool * Wt^T  -> f32 out ----------------
__global__ __launch_bounds__(256) void keys_gemm(const unsigned short* __restrict__ poolb,
                                                 const unsigned short* __restrict__ wtb,
                                                 float* __restrict__ keys_out) {
    __shared__ unsigned short As[4096], Bs[4096];
    v4f acc[4][4];
    #pragma unroll
    for (int mt = 0; mt < 4; mt++)
        #pragma unroll
        for (int nt = 0; nt < 4; nt++) acc[mt][nt] = (v4f)(0.f);

    int mbase = blockIdx.y * 128, nbase = blockIdx.x * 128;
    gemm_mainloop<D_DIM>(poolb, D_DIM, wtb, D_DIM, mbase, nbase, As, Bs, acc);

    int tid = threadIdx.x, wid = tid >> 6, lane = tid & 63;
    int wm = wid >> 1, wn = wid & 1, quad = lane >> 4, l16 = lane & 15;
    #pragma unroll
    for (int mt = 0; mt < 4; mt++)
        #pragma unroll
        for (int nt = 0; nt < 4; nt++)
            #pragma unroll
            for (int r = 0; r < 4; r++) {
                int row = mbase + wm * 64 + mt * 16 + quad * 4 + r;
                int col = nbase + wn * 64 + nt * 16 + l16;
                keys_out[(size_t)row * C_DIM + col] = acc[mt][nt][r];
            }
}

// ---------------- K4: normalize keys per (n, aspect) -> K^ bf16 [N][C] ----------------
__global__ __launch_bounds__(256) void norm_keys(const float* __restrict__ keys,
                                                 unsigned short* __restrict__ kb) {
    int tid = threadIdx.x;
    int w = tid >> 6, lane = tid & 63;
    int n = blockIdx.x * 4 + w;
    const float* rowp = keys + (size_t)n * C_DIM + lane * 8;
    float4 v0 = *(const float4*)rowp;
    float4 v1 = *(const float4*)(rowp + 4);
    float ss = v0.x * v0.x + v0.y * v0.y + v0.z * v0.z + v0.w * v0.w +
               v1.x * v1.x + v1.y * v1.y + v1.z * v1.z + v1.w * v1.w;
    // segment = 64 elems = 8 lanes; reduce within 8-lane group
    ss += __shfl_xor(ss, 1, 64);
    ss += __shfl_xor(ss, 2, 64);
    ss += __shfl_xor(ss, 4, 64);
    float sc = 1.0f / (sqrtf(ss) + 1e-8f);
    uint4 o;
    o.x = f2bf(v0.x * sc) | (f2bf(v0.y * sc) << 16);
    o.y = f2bf(v0.z * sc) | (f2bf(v0.w * sc) << 16);
    o.z = f2bf(v1.x * sc) | (f2bf(v1.y * sc) << 16);
    o.w = f2bf(v1.z * sc) | (f2bf(v1.w * sc) << 16);
    *(uint4*)(kb + (size_t)n * C_DIM + lane * 8) = o;
}

// ---------------- K5: scores = Qw * K^T, epilogue: scores f32 + row-partials of alpha_raw ----------------
__global__ __launch_bounds__(256) void scores_gemm(const unsigned short* __restrict__ qwb,
                                                   const unsigned short* __restrict__ kb,
                                                   float* __restrict__ scores_out,
                                                   float* __restrict__ partials,
                                                   const float* __restrict__ lam_p,
                                                   const float* __restrict__ tau_p,
                                                   const float* __restrict__ temp_p) {
    __shared__ unsigned short As[4096], Bs[4096];
    __shared__ float rowpart[128];
    v4f acc[4][4];
    #pragma unroll
    for (int mt = 0; mt < 4; mt++)
        #pragma unroll
        for (int nt = 0; nt < 4; nt++) acc[mt][nt] = (v4f)(0.f);

    int mbase = blockIdx.y * 128, nbase = blockIdx.x * 128;
    gemm_mainloop<C_DIM>(qwb, C_DIM, kb, C_DIM, mbase, nbase, As, Bs, acc);

    int tid = threadIdx.x, wid = tid >> 6, lane = tid & 63;
    int wm = wid >> 1, wn = wid & 1, quad = lane >> 4, l16 = lane & 15;

    if (tid < 128) rowpart[tid] = 0.f;
    __syncthreads();

    float lam = lam_p[0], tau = tau_p[0], invT = 1.0f / temp_p[0];
    float rsum[4][4];
    #pragma unroll
    for (int mt = 0; mt < 4; mt++)
        #pragma unroll
        for (int r = 0; r < 4; r++) rsum[mt][r] = 0.f;

    #pragma unroll
    for (int mt = 0; mt < 4; mt++)
        #pragma unroll
        for (int nt = 0; nt < 4; nt++)
            #pragma unroll
            for (int r = 0; r < 4; r++) {
                float s = acc[mt][nt][r];
                int row = mbase + wm * 64 + mt * 16 + quad * 4 + r;
                int col = nbase + wn * 64 + nt * 16 + l16;
                scores_out[(size_t)row * N_DIM + col] = s;
                float g = 1.0f / (1.0f + __expf(-lam * (s - tau)));
                rsum[mt][r] += g * __expf(s * invT);
            }
    #pragma unroll
    for (int mt = 0; mt < 4; mt++)
        #pragma unroll
        for (int r = 0; r < 4; r++) {
            float v = rsum[mt][r];
            v += __shfl_xor(v, 1, 64);
            v += __shfl_xor(v, 2, 64);
            v += __shfl_xor(v, 4, 64);
            v += __shfl_xor(v, 8, 64);
            if (l16 == 0)
                atomicAdd(&rowpart[wm * 64 + mt * 16 + quad * 4 + r], v);
        }
    __syncthreads();
    if (tid < 128)
        partials[(size_t)blockIdx.x * B_DIM + mbase + tid] = rowpart[tid];
}

// ---------------- K6: reduce partials -> 1/(sum+1e-8) ----------------
__global__ void reduce_sums(const float* __restrict__ partials, float* __restrict__ invs) {
    int b = threadIdx.x;   // 512 threads
    float s = 0.f;
    for (int j = 0; j < 64; j++) s += partials[(size_t)j * B_DIM + b];
    invs[b] = 1.0f / (s + 1e-8f);
}

// ---------------- K7: alpha = g*exp(s/T) * inv_sum ----------------
__global__ __launch_bounds__(256) void alpha_kernel(const float* __restrict__ scores,
                                                    const float* __restrict__ invs,
                                                    float* __restrict__ alpha,
                                                    const float* __restrict__ lam_p,
                                                    const float* __restrict__ tau_p,
                                                    const float* __restrict__ temp_p) {
    int v = blockIdx.x * 256 + threadIdx.x;   // float4 index, 0..1048575
    float lam = lam_p[0], tau = tau_p[0], invT = 1.0f / temp_p[0];
    int b = v >> 11;                           // 2048 float4 per row of 8192
    float inv = invs[b];
    float4 s4 = ((const float4*)scores)[v];
    float4 o;
    o.x = (1.0f / (1.0f + __expf(-lam * (s4.x - tau)))) * __expf(s4.x * invT) * inv;
    o.y = (1.0f / (1.0f + __expf(-lam * (s4.y - tau)))) * __expf(s4.y * invT) * inv;
    o.z = (1.0f / (1.0f + __expf(-lam * (s4.z - tau)))) * __expf(s4.z * invT) * inv;
    o.w = (1.0f / (1.0f + __expf(-lam * (s4.w - tau)))) * __expf(s4.w * invT) * inv;
    ((float4*)alpha)[v] = o;
}

extern "C" void kernel_launch(void* const* d_in, const int* in_sizes, int n_in,
                              void* d_out, int out_size, void* d_ws, size_t ws_size,
                              hipStream_t stream) {
    const float* z      = (const float*)d_in[0];
    const float* pool   = (const float*)d_in[1];
    const float* W_Q    = (const float*)d_in[2];
    const float* W_K    = (const float*)d_in[3];
    const float* logits = (const float*)d_in[4];
    const float* tau    = (const float*)d_in[5];
    const float* lam    = (const float*)d_in[6];
    const float* temp   = (const float*)d_in[7];

    float* alpha  = (float*)d_out;
    float* scores = alpha + (size_t)B_DIM * N_DIM;
    float* keys   = scores + (size_t)B_DIM * N_DIM;

    // pool bf16 lives in the alpha output region (16.78 MB, dead until K7 writes it)
    unsigned short* poolb = (unsigned short*)alpha;

    char* ws = (char*)d_ws;
    unsigned short* kb  = (unsigned short*)ws;               // 8,388,608 B
    unsigned short* wtb = (unsigned short*)(ws + 8388608);   // 1,048,576 B
    unsigned short* qwb = (unsigned short*)(ws + 9437184);   //   524,288 B
    float* partials     = (float*)(ws + 9961472);            //   131,072 B
    float* invs         = (float*)(ws + 10092544);           //     2,048 B

    cvt_pool<<<dim3(4096), dim3(256), 0, stream>>>(pool, poolb);
    cvt_wk<<<dim3(512), dim3(256), 0, stream>>>(W_K, wtb);
    prep_q<<<dim3(8, 8), dim3(256), 0, stream>>>(z, W_Q, logits, qwb);
    keys_gemm<<<dim3(4, 64), dim3(256), 0, stream>>>(poolb, wtb, keys);
    norm_keys<<<dim3(2048), dim3(256), 0, stream>>>(keys, kb);
    scores_gemm<<<dim3(64, 4), dim3(256), 0, stream>>>(qwb, kb, scores, partials,
                                                       lam, tau, temp);
    reduce_sums<<<dim3(1), dim3(512), 0, stream>>>(partials, invs);
    alpha_kernel<<<dim3(4096), dim3(256), 0, stream>>>(scores, invs, alpha,
                                                       lam, tau, temp);
}

// Round 2
// 182.462 us; speedup vs baseline: 1.6758x; 1.6758x over previous
//
#include <hip/hip_runtime.h>
#include <stdint.h>

#define B_DIM 512
#define N_DIM 8192
#define D_DIM 1024
#define DA_DIM 512
#define S_DIM 8
#define DK_DIM 64
#define C_DIM 512   // S_DIM * DK_DIM

typedef short v8s __attribute__((ext_vector_type(8)));
typedef float v4f __attribute__((ext_vector_type(4)));

__device__ __forceinline__ unsigned int f2bf(float x) {
    union { float f; unsigned int u; } v; v.f = x;
    unsigned int u = v.u;
    return (u + 0x7fffu + ((u >> 16) & 1u)) >> 16;   // RNE f32 -> bf16
}

// ---------------- K0: pool f32 -> bf16 ----------------
__global__ __launch_bounds__(256) void cvt_pool(const float* __restrict__ src,
                                                unsigned short* __restrict__ dst) {
    int t = blockIdx.x * 256 + threadIdx.x;          // 8 floats each
    const float4* s4 = (const float4*)src;
    float4 a = s4[2 * t], b = s4[2 * t + 1];
    uint4 o;
    o.x = f2bf(a.x) | (f2bf(a.y) << 16);
    o.y = f2bf(a.z) | (f2bf(a.w) << 16);
    o.z = f2bf(b.x) | (f2bf(b.y) << 16);
    o.w = f2bf(b.z) | (f2bf(b.w) << 16);
    ((uint4*)dst)[t] = o;
}

// ---------------- cvt_z: z f32 [B][DA] -> bf16 ----------------
__global__ __launch_bounds__(256) void cvt_z(const float* __restrict__ src,
                                             unsigned short* __restrict__ dst) {
    int t = blockIdx.x * 256 + threadIdx.x;          // 8 floats each, 32768 total
    const float4* s4 = (const float4*)src;
    float4 a = s4[2 * t], b = s4[2 * t + 1];
    uint4 o;
    o.x = f2bf(a.x) | (f2bf(a.y) << 16);
    o.y = f2bf(a.z) | (f2bf(a.w) << 16);
    o.z = f2bf(b.x) | (f2bf(b.y) << 16);
    o.w = f2bf(b.z) | (f2bf(b.w) << 16);
    ((uint4*)dst)[t] = o;
}

// ---------------- transpose-convert: W [S][Dx][DK] f32 -> Wt bf16 [C][Dx] ----------------
__global__ __launch_bounds__(256) void cvt_w_t(const float* __restrict__ w,
                                               unsigned short* __restrict__ wt,
                                               int ddim) {
    int c = blockIdx.x;                               // 0..511
    int a = c >> 6, k = c & 63;
    const float* src = w + (size_t)a * ddim * DK_DIM + k;
    unsigned short* drow = wt + (size_t)c * ddim;
    for (int d = threadIdx.x; d < ddim; d += 256)
        drow[d] = (unsigned short)f2bf(src[(size_t)d * DK_DIM]);
}

// ---------------- shared MFMA mainloop: C[128x128] = A[128xK] * B[128xK]^T ----------------
template <int KDIM>
__device__ __forceinline__ void gemm_mainloop(const unsigned short* __restrict__ A, int lda,
                                              const unsigned short* __restrict__ Bm, int ldb,
                                              int mbase, int nbase,
                                              unsigned short* As, unsigned short* Bs,
                                              v4f acc[4][4]) {
    int tid = threadIdx.x;
    int wid = tid >> 6, lane = tid & 63;
    int wm = wid >> 1, wn = wid & 1;
    int quad = lane >> 4, l16 = lane & 15;
    int srow = tid >> 2, scg = (tid & 3) * 8;

    for (int kk = 0; kk < KDIM / 32; kk++) {
        #pragma unroll
        for (int j = 0; j < 2; j++) {
            int row = srow + j * 64;
            *(uint4*)&As[row * 32 + scg] =
                *(const uint4*)&A[(size_t)(mbase + row) * lda + kk * 32 + scg];
            *(uint4*)&Bs[row * 32 + scg] =
                *(const uint4*)&Bm[(size_t)(nbase + row) * ldb + kk * 32 + scg];
        }
        __syncthreads();
        v8s af[4], bf[4];
        #pragma unroll
        for (int mt = 0; mt < 4; mt++)
            af[mt] = *(const v8s*)&As[(wm * 64 + mt * 16 + l16) * 32 + quad * 8];
        #pragma unroll
        for (int nt = 0; nt < 4; nt++)
            bf[nt] = *(const v8s*)&Bs[(wn * 64 + nt * 16 + l16) * 32 + quad * 8];
        #pragma unroll
        for (int mt = 0; mt < 4; mt++)
            #pragma unroll
            for (int nt = 0; nt < 4; nt++)
                acc[mt][nt] = __builtin_amdgcn_mfma_f32_16x16x32_bf16(
                    af[mt], bf[nt], acc[mt][nt], 0, 0, 0);
        __syncthreads();
    }
}

// ---------------- plain A*B^T GEMM -> f32 (used for queries and keys) ----------------
template <int KDIM>
__global__ __launch_bounds__(256) void gemm_bt(const unsigned short* __restrict__ A,
                                               const unsigned short* __restrict__ Bm,
                                               float* __restrict__ out, int ldo) {
    __shared__ unsigned short As[4096], Bs[4096];
    v4f acc[4][4];
    #pragma unroll
    for (int mt = 0; mt < 4; mt++)
        #pragma unroll
        for (int nt = 0; nt < 4; nt++) acc[mt][nt] = (v4f)(0.f);

    int mbase = blockIdx.y * 128, nbase = blockIdx.x * 128;
    gemm_mainloop<KDIM>(A, KDIM, Bm, KDIM, mbase, nbase, As, Bs, acc);

    int tid = threadIdx.x, wid = tid >> 6, lane = tid & 63;
    int wm = wid >> 1, wn = wid & 1, quad = lane >> 4, l16 = lane & 15;
    #pragma unroll
    for (int mt = 0; mt < 4; mt++)
        #pragma unroll
        for (int nt = 0; nt < 4; nt++)
            #pragma unroll
            for (int r = 0; r < 4; r++) {
                int row = mbase + wm * 64 + mt * 16 + quad * 4 + r;
                int col = nbase + wn * 64 + nt * 16 + l16;
                out[(size_t)row * ldo + col] = acc[mt][nt][r];
            }
}

// ---------------- norm_q: queries f32 [B][C] -> normalize per 64-seg, * softmax(w), bf16 ----------------
__global__ __launch_bounds__(256) void norm_q(const float* __restrict__ qf,
                                              const float* __restrict__ logits,
                                              unsigned short* __restrict__ qwb) {
    int tid = threadIdx.x;
    int w = tid >> 6, lane = tid & 63;
    int b = blockIdx.x * 4 + w;                       // 128 blocks * 4 rows

    // softmax over 8 logits
    float l[8]; float mx = -1e30f;
    #pragma unroll
    for (int i = 0; i < 8; i++) { l[i] = logits[i]; mx = fmaxf(mx, l[i]); }
    float se = 0.f;
    #pragma unroll
    for (int i = 0; i < 8; i++) { l[i] = __expf(l[i] - mx); se += l[i]; }
    int aspect = lane >> 3;                           // 8 lanes per 64-elem segment
    float wa = l[aspect] / se;

    const float* rowp = qf + (size_t)b * C_DIM + lane * 8;
    float4 v0 = *(const float4*)rowp;
    float4 v1 = *(const float4*)(rowp + 4);
    float ss = v0.x * v0.x + v0.y * v0.y + v0.z * v0.z + v0.w * v0.w +
               v1.x * v1.x + v1.y * v1.y + v1.z * v1.z + v1.w * v1.w;
    ss += __shfl_xor(ss, 1, 64);
    ss += __shfl_xor(ss, 2, 64);
    ss += __shfl_xor(ss, 4, 64);
    float sc = wa / (sqrtf(ss) + 1e-8f);
    uint4 o;
    o.x = f2bf(v0.x * sc) | (f2bf(v0.y * sc) << 16);
    o.y = f2bf(v0.z * sc) | (f2bf(v0.w * sc) << 16);
    o.z = f2bf(v1.x * sc) | (f2bf(v1.y * sc) << 16);
    o.w = f2bf(v1.z * sc) | (f2bf(v1.w * sc) << 16);
    *(uint4*)(qwb + (size_t)b * C_DIM + lane * 8) = o;
}

// ---------------- norm_keys: per (n, aspect) rsqrt -> K^ bf16 [N][C] ----------------
__global__ __launch_bounds__(256) void norm_keys(const float* __restrict__ keys,
                                                 unsigned short* __restrict__ kb) {
    int tid = threadIdx.x;
    int w = tid >> 6, lane = tid & 63;
    int n = blockIdx.x * 4 + w;
    const float* rowp = keys + (size_t)n * C_DIM + lane * 8;
    float4 v0 = *(const float4*)rowp;
    float4 v1 = *(const float4*)(rowp + 4);
    float ss = v0.x * v0.x + v0.y * v0.y + v0.z * v0.z + v0.w * v0.w +
               v1.x * v1.x + v1.y * v1.y + v1.z * v1.z + v1.w * v1.w;
    ss += __shfl_xor(ss, 1, 64);
    ss += __shfl_xor(ss, 2, 64);
    ss += __shfl_xor(ss, 4, 64);
    float sc = 1.0f / (sqrtf(ss) + 1e-8f);
    uint4 o;
    o.x = f2bf(v0.x * sc) | (f2bf(v0.y * sc) << 16);
    o.y = f2bf(v0.z * sc) | (f2bf(v0.w * sc) << 16);
    o.z = f2bf(v1.x * sc) | (f2bf(v1.y * sc) << 16);
    o.w = f2bf(v1.z * sc) | (f2bf(v1.w * sc) << 16);
    *(uint4*)(kb + (size_t)n * C_DIM + lane * 8) = o;
}

// ---------------- scores_gemm: scores = Qw * K^T + epilogue partial row-sums ----------------
__global__ __launch_bounds__(256) void scores_gemm(const unsigned short* __restrict__ qwb,
                                                   const unsigned short* __restrict__ kb,
                                                   float* __restrict__ scores_out,
                                                   float* __restrict__ partials,
                                                   const float* __restrict__ lam_p,
                                                   const float* __restrict__ tau_p,
                                                   const float* __restrict__ temp_p) {
    __shared__ unsigned short As[4096], Bs[4096];
    __shared__ float rowpart[128];
    v4f acc[4][4];
    #pragma unroll
    for (int mt = 0; mt < 4; mt++)
        #pragma unroll
        for (int nt = 0; nt < 4; nt++) acc[mt][nt] = (v4f)(0.f);

    int mbase = blockIdx.y * 128, nbase = blockIdx.x * 128;
    gemm_mainloop<C_DIM>(qwb, C_DIM, kb, C_DIM, mbase, nbase, As, Bs, acc);

    int tid = threadIdx.x, wid = tid >> 6, lane = tid & 63;
    int wm = wid >> 1, wn = wid & 1, quad = lane >> 4, l16 = lane & 15;

    if (tid < 128) rowpart[tid] = 0.f;
    __syncthreads();

    float lam = lam_p[0], tau = tau_p[0], invT = 1.0f / temp_p[0];
    float rsum[4][4];
    #pragma unroll
    for (int mt = 0; mt < 4; mt++)
        #pragma unroll
        for (int r = 0; r < 4; r++) rsum[mt][r] = 0.f;

    #pragma unroll
    for (int mt = 0; mt < 4; mt++)
        #pragma unroll
        for (int nt = 0; nt < 4; nt++)
            #pragma unroll
            for (int r = 0; r < 4; r++) {
                float s = acc[mt][nt][r];
                int row = mbase + wm * 64 + mt * 16 + quad * 4 + r;
                int col = nbase + wn * 64 + nt * 16 + l16;
                scores_out[(size_t)row * N_DIM + col] = s;
                float g = 1.0f / (1.0f + __expf(-lam * (s - tau)));
                rsum[mt][r] += g * __expf(s * invT);
            }
    #pragma unroll
    for (int mt = 0; mt < 4; mt++)
        #pragma unroll
        for (int r = 0; r < 4; r++) {
            float v = rsum[mt][r];
            v += __shfl_xor(v, 1, 64);
            v += __shfl_xor(v, 2, 64);
            v += __shfl_xor(v, 4, 64);
            v += __shfl_xor(v, 8, 64);
            if (l16 == 0)
                atomicAdd(&rowpart[wm * 64 + mt * 16 + quad * 4 + r], v);
        }
    __syncthreads();
    if (tid < 128)
        partials[(size_t)blockIdx.x * B_DIM + mbase + tid] = rowpart[tid];
}

// ---------------- reduce partials -> 1/(sum+1e-8) ----------------
__global__ void reduce_sums(const float* __restrict__ partials, float* __restrict__ invs) {
    int b = threadIdx.x;   // 512 threads
    float s = 0.f;
    for (int j = 0; j < 64; j++) s += partials[(size_t)j * B_DIM + b];
    invs[b] = 1.0f / (s + 1e-8f);
}

// ---------------- alpha = g*exp(s/T) * inv_sum ----------------
__global__ __launch_bounds__(256) void alpha_kernel(const float* __restrict__ scores,
                                                    const float* __restrict__ invs,
                                                    float* __restrict__ alpha,
                                                    const float* __restrict__ lam_p,
                                                    const float* __restrict__ tau_p,
                                                    const float* __restrict__ temp_p) {
    int v = blockIdx.x * 256 + threadIdx.x;   // float4 index
    float lam = lam_p[0], tau = tau_p[0], invT = 1.0f / temp_p[0];
    int b = v >> 11;                           // 2048 float4 per row of 8192
    float inv = invs[b];
    float4 s4 = ((const float4*)scores)[v];
    float4 o;
    o.x = (1.0f / (1.0f + __expf(-lam * (s4.x - tau)))) * __expf(s4.x * invT) * inv;
    o.y = (1.0f / (1.0f + __expf(-lam * (s4.y - tau)))) * __expf(s4.y * invT) * inv;
    o.z = (1.0f / (1.0f + __expf(-lam * (s4.z - tau)))) * __expf(s4.z * invT) * inv;
    o.w = (1.0f / (1.0f + __expf(-lam * (s4.w - tau)))) * __expf(s4.w * invT) * inv;
    ((float4*)alpha)[v] = o;
}

extern "C" void kernel_launch(void* const* d_in, const int* in_sizes, int n_in,
                              void* d_out, int out_size, void* d_ws, size_t ws_size,
                              hipStream_t stream) {
    const float* z      = (const float*)d_in[0];
    const float* pool   = (const float*)d_in[1];
    const float* W_Q    = (const float*)d_in[2];
    const float* W_K    = (const float*)d_in[3];
    const float* logits = (const float*)d_in[4];
    const float* tau    = (const float*)d_in[5];
    const float* lam    = (const float*)d_in[6];
    const float* temp   = (const float*)d_in[7];

    float* alpha  = (float*)d_out;
    float* scores = alpha + (size_t)B_DIM * N_DIM;
    float* keys   = scores + (size_t)B_DIM * N_DIM;

    // pool bf16 lives in the alpha output region (16.78 MB, dead until alpha_kernel)
    unsigned short* poolb = (unsigned short*)alpha;

    // queries scratch lives in the scores output region (dead until scores_gemm):
    //   qf  f32 [512][512]  = 1 MB
    //   zb  bf16 [512][512] = 0.5 MB
    //   wqt bf16 [512][512] = 0.5 MB
    float* qf            = scores;
    unsigned short* zb   = (unsigned short*)(scores + 262144);
    unsigned short* wqt  = zb + 262144;

    char* ws = (char*)d_ws;
    unsigned short* kb  = (unsigned short*)ws;               // 8,388,608 B
    unsigned short* wtb = (unsigned short*)(ws + 8388608);   // 1,048,576 B
    unsigned short* qwb = (unsigned short*)(ws + 9437184);   //   524,288 B
    float* partials     = (float*)(ws + 9961472);            //   131,072 B
    float* invs         = (float*)(ws + 10092544);           //     2,048 B

    // --- queries path (replaces the latency-bound prep_q) ---
    cvt_z<<<dim3(128), dim3(256), 0, stream>>>(z, zb);
    cvt_w_t<<<dim3(512), dim3(256), 0, stream>>>(W_Q, wqt, DA_DIM);
    gemm_bt<DA_DIM><<<dim3(4, 4), dim3(256), 0, stream>>>(zb, wqt, qf, C_DIM);
    norm_q<<<dim3(128), dim3(256), 0, stream>>>(qf, logits, qwb);

    // --- keys path ---
    cvt_pool<<<dim3(4096), dim3(256), 0, stream>>>(pool, poolb);
    cvt_w_t<<<dim3(512), dim3(256), 0, stream>>>(W_K, wtb, D_DIM);
    gemm_bt<D_DIM><<<dim3(4, 64), dim3(256), 0, stream>>>(poolb, wtb, keys, C_DIM);
    norm_keys<<<dim3(2048), dim3(256), 0, stream>>>(keys, kb);

    // --- scores + alpha ---
    scores_gemm<<<dim3(64, 4), dim3(256), 0, stream>>>(qwb, kb, scores, partials,
                                                       lam, tau, temp);
    reduce_sums<<<dim3(1), dim3(512), 0, stream>>>(partials, invs);
    alpha_kernel<<<dim3(4096), dim3(256), 0, stream>>>(scores, invs, alpha,
                                                       lam, tau, temp);
}

// Round 3
// 161.187 us; speedup vs baseline: 1.8970x; 1.1320x over previous
//
#include <hip/hip_runtime.h>
#include <stdint.h>

#define B_DIM 512
#define N_DIM 8192
#define D_DIM 1024
#define DA_DIM 512
#define S_DIM 8
#define DK_DIM 64
#define C_DIM 512   // S_DIM * DK_DIM

typedef short v8s __attribute__((ext_vector_type(8)));
typedef float v4f __attribute__((ext_vector_type(4)));

__device__ __forceinline__ unsigned int f2bf(float x) {
    union { float f; unsigned int u; } v; v.f = x;
    unsigned int u = v.u;
    return (u + 0x7fffu + ((u >> 16) & 1u)) >> 16;   // RNE f32 -> bf16
}

// async 16B global -> LDS (wave-uniform LDS base, data lands at base + lane*16)
__device__ __forceinline__ void gld16(const unsigned short* g, unsigned short* l) {
    __builtin_amdgcn_global_load_lds(
        (const __attribute__((address_space(1))) unsigned int*)g,
        (__attribute__((address_space(3))) unsigned int*)l,
        16, 0, 0);
}

// ---------------- K0: prep — all input conversions in one dispatch ----------------
__device__ __forceinline__ void cvt8(const float* __restrict__ src,
                                     unsigned short* __restrict__ dst, int t) {
    const float4* s4 = (const float4*)src;
    float4 a = s4[2 * t], b = s4[2 * t + 1];
    uint4 o;
    o.x = f2bf(a.x) | (f2bf(a.y) << 16);
    o.y = f2bf(a.z) | (f2bf(a.w) << 16);
    o.z = f2bf(b.x) | (f2bf(b.y) << 16);
    o.w = f2bf(b.z) | (f2bf(b.w) << 16);
    ((uint4*)dst)[t] = o;
}

__device__ __forceinline__ void w_transpose(const float* __restrict__ w,
                                            unsigned short* __restrict__ wt,
                                            int c, int ddim) {
    int a = c >> 6, k = c & 63;
    const float* src = w + (size_t)a * ddim * DK_DIM + k;
    unsigned short* drow = wt + (size_t)c * ddim;
    for (int d = threadIdx.x; d < ddim; d += 256)
        drow[d] = (unsigned short)f2bf(src[(size_t)d * DK_DIM]);
}

__global__ __launch_bounds__(256) void prep(const float* __restrict__ pool,
                                            const float* __restrict__ z,
                                            const float* __restrict__ W_Q,
                                            const float* __restrict__ W_K,
                                            unsigned short* __restrict__ poolb,
                                            unsigned short* __restrict__ zb,
                                            unsigned short* __restrict__ wqt,
                                            unsigned short* __restrict__ wtb) {
    int blk = blockIdx.x;
    if (blk < 4096) {
        cvt8(pool, poolb, blk * 256 + threadIdx.x);
    } else if (blk < 4224) {
        cvt8(z, zb, (blk - 4096) * 256 + threadIdx.x);
    } else if (blk < 4736) {
        w_transpose(W_K, wtb, blk - 4224, D_DIM);
    } else {
        w_transpose(W_Q, wqt, blk - 4736, DA_DIM);
    }
}

// ---------------- MFMA mainloop with async global->LDS staging ----------------
// C[128x128] += A[128xK] * B[128xK]^T ; As/Bs are [128 rows][32 shorts]
__device__ __forceinline__ void gemm_mainloop(const unsigned short* __restrict__ A, int lda,
                                              const unsigned short* __restrict__ Bm, int ldb,
                                              int mbase, int nbase, int kiters,
                                              unsigned short* As, unsigned short* Bs,
                                              v4f acc[4][4]) {
    int tid = threadIdx.x;
    int wid = tid >> 6, lane = tid & 63;
    int wm = wid >> 1, wn = wid & 1;
    int quad = lane >> 4, l16 = lane & 15;
    int srow = lane >> 2;            // 0..15 within a 16-row group
    int scol = (lane & 3) * 8;       // shorts (16B granules)

    for (int kk = 0; kk < kiters; kk++) {
        #pragma unroll
        for (int j = 0; j < 2; j++) {
            int rgrp = wid * 2 + j;                    // wave-uniform, 0..7
            int row = rgrp * 16 + srow;
            gld16(&A[(size_t)(mbase + row) * lda + kk * 32 + scol], &As[rgrp * 512]);
            gld16(&Bm[(size_t)(nbase + row) * ldb + kk * 32 + scol], &Bs[rgrp * 512]);
        }
        __syncthreads();
        v8s af[4], bf[4];
        #pragma unroll
        for (int mt = 0; mt < 4; mt++)
            af[mt] = *(const v8s*)&As[(wm * 64 + mt * 16 + l16) * 32 + quad * 8];
        #pragma unroll
        for (int nt = 0; nt < 4; nt++)
            bf[nt] = *(const v8s*)&Bs[(wn * 64 + nt * 16 + l16) * 32 + quad * 8];
        #pragma unroll
        for (int mt = 0; mt < 4; mt++)
            #pragma unroll
            for (int nt = 0; nt < 4; nt++)
                acc[mt][nt] = __builtin_amdgcn_mfma_f32_16x16x32_bf16(
                    af[mt], bf[nt], acc[mt][nt], 0, 0, 0);
        __syncthreads();
    }
}

// ---------------- K1: fused keys-GEMM (+norm) and queries-GEMM (+norm+weight) ----------------
// blocks [0,256): keys = poolb * wtb^T -> f32 keys_out + normalized bf16 kb
// blocks [256,272): queries = zb * wqt^T -> normalized*softmax(w) bf16 qwb
__global__ __launch_bounds__(256) void fused_gemms(const unsigned short* __restrict__ poolb,
                                                   const unsigned short* __restrict__ wtb,
                                                   const unsigned short* __restrict__ zb,
                                                   const unsigned short* __restrict__ wqt,
                                                   const float* __restrict__ logits,
                                                   float* __restrict__ keys_out,
                                                   unsigned short* __restrict__ kb,
                                                   unsigned short* __restrict__ qwb) {
    __shared__ unsigned short As[4096], Bs[4096];
    v4f acc[4][4];
    #pragma unroll
    for (int mt = 0; mt < 4; mt++)
        #pragma unroll
        for (int nt = 0; nt < 4; nt++) acc[mt][nt] = (v4f)(0.f);

    int blk = blockIdx.x;
    bool is_q = blk >= 256;
    const unsigned short* A;
    const unsigned short* Bm;
    int lda, mbase, nbase, kiters;
    if (is_q) {
        int q = blk - 256;
        A = zb; Bm = wqt; lda = DA_DIM; kiters = DA_DIM / 32;
        mbase = (q >> 2) * 128; nbase = (q & 3) * 128;
    } else {
        A = poolb; Bm = wtb; lda = D_DIM; kiters = D_DIM / 32;
        mbase = (blk >> 2) * 128; nbase = (blk & 3) * 128;
    }

    gemm_mainloop(A, lda, Bm, lda, mbase, nbase, kiters, As, Bs, acc);

    int tid = threadIdx.x, wid = tid >> 6, lane = tid & 63;
    int wm = wid >> 1, wn = wid & 1, quad = lane >> 4, l16 = lane & 15;

    if (is_q) {
        // softmax over 8 logits; this warp's 64-col segment is aspect (nbase>>6)+wn
        float l[8]; float mx = -1e30f;
        #pragma unroll
        for (int i = 0; i < 8; i++) { l[i] = logits[i]; mx = fmaxf(mx, l[i]); }
        float se = 0.f;
        #pragma unroll
        for (int i = 0; i < 8; i++) { l[i] = __expf(l[i] - mx); se += l[i]; }
        float wa = l[(nbase >> 6) + wn] / se;

        #pragma unroll
        for (int mt = 0; mt < 4; mt++)
            #pragma unroll
            for (int r = 0; r < 4; r++) {
                float ss = 0.f;
                #pragma unroll
                for (int nt = 0; nt < 4; nt++) {
                    float s = acc[mt][nt][r];
                    ss += s * s;
                }
                ss += __shfl_xor(ss, 1, 64);
                ss += __shfl_xor(ss, 2, 64);
                ss += __shfl_xor(ss, 4, 64);
                ss += __shfl_xor(ss, 8, 64);
                float sc = wa / (sqrtf(ss) + 1e-8f);
                int row = mbase + wm * 64 + mt * 16 + quad * 4 + r;
                #pragma unroll
                for (int nt = 0; nt < 4; nt++) {
                    int col = nbase + wn * 64 + nt * 16 + l16;
                    qwb[(size_t)row * C_DIM + col] =
                        (unsigned short)f2bf(acc[mt][nt][r] * sc);
                }
            }
    } else {
        #pragma unroll
        for (int mt = 0; mt < 4; mt++)
            #pragma unroll
            for (int r = 0; r < 4; r++) {
                float ss = 0.f;
                #pragma unroll
                for (int nt = 0; nt < 4; nt++) {
                    float s = acc[mt][nt][r];
                    ss += s * s;
                }
                ss += __shfl_xor(ss, 1, 64);
                ss += __shfl_xor(ss, 2, 64);
                ss += __shfl_xor(ss, 4, 64);
                ss += __shfl_xor(ss, 8, 64);
                float sc = 1.0f / (sqrtf(ss) + 1e-8f);
                int row = mbase + wm * 64 + mt * 16 + quad * 4 + r;
                #pragma unroll
                for (int nt = 0; nt < 4; nt++) {
                    int col = nbase + wn * 64 + nt * 16 + l16;
                    float s = acc[mt][nt][r];
                    keys_out[(size_t)row * C_DIM + col] = s;
                    kb[(size_t)row * C_DIM + col] = (unsigned short)f2bf(s * sc);
                }
            }
    }
}

// ---------------- K2: scores = Qw * K^T + epilogue partial row-sums ----------------
__global__ __launch_bounds__(256) void scores_gemm(const unsigned short* __restrict__ qwb,
                                                   const unsigned short* __restrict__ kb,
                                                   float* __restrict__ scores_out,
                                                   float* __restrict__ partials,
                                                   const float* __restrict__ lam_p,
                                                   const float* __restrict__ tau_p,
                                                   const float* __restrict__ temp_p) {
    __shared__ unsigned short As[4096], Bs[4096];
    __shared__ float rowpart[128];
    v4f acc[4][4];
    #pragma unroll
    for (int mt = 0; mt < 4; mt++)
        #pragma unroll
        for (int nt = 0; nt < 4; nt++) acc[mt][nt] = (v4f)(0.f);

    int mbase = blockIdx.y * 128, nbase = blockIdx.x * 128;
    gemm_mainloop(qwb, C_DIM, kb, C_DIM, mbase, nbase, C_DIM / 32, As, Bs, acc);

    int tid = threadIdx.x, wid = tid >> 6, lane = tid & 63;
    int wm = wid >> 1, wn = wid & 1, quad = lane >> 4, l16 = lane & 15;

    if (tid < 128) rowpart[tid] = 0.f;
    __syncthreads();

    float lam = lam_p[0], tau = tau_p[0], invT = 1.0f / temp_p[0];
    float rsum[4][4];
    #pragma unroll
    for (int mt = 0; mt < 4; mt++)
        #pragma unroll
        for (int r = 0; r < 4; r++) rsum[mt][r] = 0.f;

    #pragma unroll
    for (int mt = 0; mt < 4; mt++)
        #pragma unroll
        for (int nt = 0; nt < 4; nt++)
            #pragma unroll
            for (int r = 0; r < 4; r++) {
                float s = acc[mt][nt][r];
                int row = mbase + wm * 64 + mt * 16 + quad * 4 + r;
                int col = nbase + wn * 64 + nt * 16 + l16;
                scores_out[(size_t)row * N_DIM + col] = s;
                float g = 1.0f / (1.0f + __expf(-lam * (s - tau)));
                rsum[mt][r] += g * __expf(s * invT);
            }
    #pragma unroll
    for (int mt = 0; mt < 4; mt++)
        #pragma unroll
        for (int r = 0; r < 4; r++) {
            float v = rsum[mt][r];
            v += __shfl_xor(v, 1, 64);
            v += __shfl_xor(v, 2, 64);
            v += __shfl_xor(v, 4, 64);
            v += __shfl_xor(v, 8, 64);
            if (l16 == 0)
                atomicAdd(&rowpart[wm * 64 + mt * 16 + quad * 4 + r], v);
        }
    __syncthreads();
    if (tid < 128)
        partials[(size_t)blockIdx.x * B_DIM + mbase + tid] = rowpart[tid];
}

// ---------------- K3: alpha = g*exp(s/T) / rowsum  (partials reduced in-kernel) ----------------
__global__ __launch_bounds__(256) void alpha_kernel(const float* __restrict__ scores,
                                                    const float* __restrict__ partials,
                                                    float* __restrict__ alpha,
                                                    const float* __restrict__ lam_p,
                                                    const float* __restrict__ tau_p,
                                                    const float* __restrict__ temp_p) {
    __shared__ float s_inv;
    int b = blockIdx.x;                       // one row per block, 512 blocks
    int tid = threadIdx.x;
    if (tid < 64) {
        float v = partials[(size_t)tid * B_DIM + b];
        v += __shfl_xor(v, 1, 64);
        v += __shfl_xor(v, 2, 64);
        v += __shfl_xor(v, 4, 64);
        v += __shfl_xor(v, 8, 64);
        v += __shfl_xor(v, 16, 64);
        v += __shfl_xor(v, 32, 64);
        if (tid == 0) s_inv = 1.0f / (v + 1e-8f);
    }
    __syncthreads();
    float inv = s_inv;
    float lam = lam_p[0], tau = tau_p[0], invT = 1.0f / temp_p[0];
    const float4* srow = (const float4*)(scores + (size_t)b * N_DIM);
    float4* arow = (float4*)(alpha + (size_t)b * N_DIM);
    #pragma unroll
    for (int i = 0; i < 8; i++) {
        int idx = tid + i * 256;              // 0..2047 float4
        float4 s4 = srow[idx];
        float4 o;
        o.x = (1.0f / (1.0f + __expf(-lam * (s4.x - tau)))) * __expf(s4.x * invT) * inv;
        o.y = (1.0f / (1.0f + __expf(-lam * (s4.y - tau)))) * __expf(s4.y * invT) * inv;
        o.z = (1.0f / (1.0f + __expf(-lam * (s4.z - tau)))) * __expf(s4.z * invT) * inv;
        o.w = (1.0f / (1.0f + __expf(-lam * (s4.w - tau)))) * __expf(s4.w * invT) * inv;
        arow[idx] = o;
    }
}

extern "C" void kernel_launch(void* const* d_in, const int* in_sizes, int n_in,
                              void* d_out, int out_size, void* d_ws, size_t ws_size,
                              hipStream_t stream) {
    const float* z      = (const float*)d_in[0];
    const float* pool   = (const float*)d_in[1];
    const float* W_Q    = (const float*)d_in[2];
    const float* W_K    = (const float*)d_in[3];
    const float* logits = (const float*)d_in[4];
    const float* tau    = (const float*)d_in[5];
    const float* lam    = (const float*)d_in[6];
    const float* temp   = (const float*)d_in[7];

    float* alpha  = (float*)d_out;
    float* scores = alpha + (size_t)B_DIM * N_DIM;
    float* keys   = scores + (size_t)B_DIM * N_DIM;

    // All scratch in ws (poison cost is the harness's, paid regardless).
    char* ws = (char*)d_ws;
    unsigned short* poolb = (unsigned short*)(ws);             // 16,777,216 B
    unsigned short* kb    = (unsigned short*)(ws + 16777216);  //  8,388,608 B
    unsigned short* wtb   = (unsigned short*)(ws + 25165824);  //  1,048,576 B
    unsigned short* wqt   = (unsigned short*)(ws + 26214400);  //    524,288 B
    unsigned short* zb    = (unsigned short*)(ws + 26738688);  //    524,288 B
    unsigned short* qwb   = (unsigned short*)(ws + 27262976);  //    524,288 B
    float* partials       = (float*)(ws + 27787264);           //    131,072 B

    prep<<<dim3(5248), dim3(256), 0, stream>>>(pool, z, W_Q, W_K,
                                               poolb, zb, wqt, wtb);
    fused_gemms<<<dim3(272), dim3(256), 0, stream>>>(poolb, wtb, zb, wqt, logits,
                                                     keys, kb, qwb);
    scores_gemm<<<dim3(64, 4), dim3(256), 0, stream>>>(qwb, kb, scores, partials,
                                                       lam, tau, temp);
    alpha_kernel<<<dim3(512), dim3(256), 0, stream>>>(scores, partials, alpha,
                                                      lam, tau, temp);
}

// Round 4
// 157.876 us; speedup vs baseline: 1.9368x; 1.0210x over previous
//
#include <hip/hip_runtime.h>
#include <stdint.h>

#define B_DIM 512
#define N_DIM 8192
#define D_DIM 1024
#define DA_DIM 512
#define S_DIM 8
#define DK_DIM 64
#define C_DIM 512   // S_DIM * DK_DIM

typedef short v8s __attribute__((ext_vector_type(8)));
typedef float v4f __attribute__((ext_vector_type(4)));

__device__ __forceinline__ unsigned int f2bf(float x) {
    union { float f; unsigned int u; } v; v.f = x;
    unsigned int u = v.u;
    return (u + 0x7fffu + ((u >> 16) & 1u)) >> 16;   // RNE f32 -> bf16
}

// async 16B global -> LDS (wave-uniform LDS base, data lands at base + lane*16)
__device__ __forceinline__ void gld16(const unsigned short* g, unsigned short* l) {
    __builtin_amdgcn_global_load_lds(
        (const __attribute__((address_space(1))) unsigned int*)g,
        (__attribute__((address_space(3))) unsigned int*)l,
        16, 0, 0);
}

// ---------------- prep: all input conversions in one dispatch ----------------
__device__ __forceinline__ void cvt8(const float* __restrict__ src,
                                     unsigned short* __restrict__ dst, int t) {
    const float4* s4 = (const float4*)src;
    float4 a = s4[2 * t], b = s4[2 * t + 1];
    uint4 o;
    o.x = f2bf(a.x) | (f2bf(a.y) << 16);
    o.y = f2bf(a.z) | (f2bf(a.w) << 16);
    o.z = f2bf(b.x) | (f2bf(b.y) << 16);
    o.w = f2bf(b.z) | (f2bf(b.w) << 16);
    ((uint4*)dst)[t] = o;
}

// Transpose one 64(d) x 64(k) tile of W[a][d][k] f32 -> wt[c=a*64+k][d] bf16,
// LDS round-trip so both global phases are coalesced.
__device__ __forceinline__ void w_transpose_tile(const float* __restrict__ w,
                                                 unsigned short* __restrict__ wt,
                                                 int a, int dt, int ddim,
                                                 unsigned short* T /* [64*68] */) {
    int t = threadIdx.x;
    int d0 = dt * 64;
    int kc4 = (t & 15) * 4;
    const float4* src = (const float4*)(w + ((size_t)a * ddim + d0) * DK_DIM);
    #pragma unroll
    for (int p = 0; p < 4; p++) {
        int dr = p * 16 + (t >> 4);
        float4 v = src[dr * 16 + (t & 15)];   // coalesced: 16 lanes cover one 256B row
        uint2 pk;
        pk.x = f2bf(v.x) | (f2bf(v.y) << 16);
        pk.y = f2bf(v.z) | (f2bf(v.w) << 16);
        *(uint2*)&T[dr * 68 + kc4] = pk;      // 8B-aligned (68*2=136, kc4*2 mult of 8)
    }
    __syncthreads();
    int c0 = a * 64;
    #pragma unroll
    for (int q = 0; q < 2; q++) {
        int k = q * 32 + (t >> 3);
        int ch = t & 7;
        unsigned short s[8];
        #pragma unroll
        for (int i = 0; i < 8; i++) s[i] = T[(ch * 8 + i) * 68 + k];
        uint4 o;
        o.x = (unsigned)s[0] | ((unsigned)s[1] << 16);
        o.y = (unsigned)s[2] | ((unsigned)s[3] << 16);
        o.z = (unsigned)s[4] | ((unsigned)s[5] << 16);
        o.w = (unsigned)s[6] | ((unsigned)s[7] << 16);
        // coalesced: 8 lanes cover 128B of row c0+k
        *(uint4*)&wt[(size_t)(c0 + k) * ddim + d0 + ch * 8] = o;
    }
}

__global__ __launch_bounds__(256) void prep(const float* __restrict__ pool,
                                            const float* __restrict__ z,
                                            const float* __restrict__ W_Q,
                                            const float* __restrict__ W_K,
                                            unsigned short* __restrict__ poolb,
                                            unsigned short* __restrict__ zb,
                                            unsigned short* __restrict__ wqt,
                                            unsigned short* __restrict__ wtb) {
    __shared__ unsigned short T[64 * 68];
    int blk = blockIdx.x;
    if (blk < 4096) {
        cvt8(pool, poolb, blk * 256 + threadIdx.x);
    } else if (blk < 4224) {
        cvt8(z, zb, (blk - 4096) * 256 + threadIdx.x);
    } else if (blk < 4352) {
        int idx = blk - 4224;                      // W_K: 8 aspects x 16 d-tiles
        w_transpose_tile(W_K, wtb, idx >> 4, idx & 15, D_DIM, T);
    } else {
        int idx = blk - 4352;                      // W_Q: 8 aspects x 8 d-tiles
        w_transpose_tile(W_Q, wqt, idx >> 3, idx & 7, DA_DIM, T);
    }
}

// ---------------- double-buffered MFMA mainloop with async prefetch ----------------
// C[128x128] += A[128xK] * B[128xK]^T ; As/Bs: 2 buffers of [128 rows][32 shorts]
__device__ __forceinline__ void gemm_mainloop(const unsigned short* __restrict__ A, int lda,
                                              const unsigned short* __restrict__ Bm, int ldb,
                                              int mbase, int nbase, int kiters,
                                              unsigned short (*As)[4096],
                                              unsigned short (*Bs)[4096],
                                              v4f acc[4][4]) {
    int tid = threadIdx.x;
    int wid = tid >> 6, lane = tid & 63;
    int wm = wid >> 1, wn = wid & 1;
    int quad = lane >> 4, l16 = lane & 15;
    int srow = lane >> 2;            // 0..15 within a 16-row group
    int scol = (lane & 3) * 8;       // shorts (16B granules)

    auto stage = [&](int kk, int p) {
        #pragma unroll
        for (int j = 0; j < 2; j++) {
            int rgrp = wid * 2 + j;                    // wave-uniform, 0..7
            int row = rgrp * 16 + srow;
            gld16(&A[(size_t)(mbase + row) * lda + kk * 32 + scol], &As[p][rgrp * 512]);
            gld16(&Bm[(size_t)(nbase + row) * ldb + kk * 32 + scol], &Bs[p][rgrp * 512]);
        }
    };

    stage(0, 0);
    for (int kk = 0; kk < kiters; kk++) {
        __syncthreads();                       // drains stage(kk) loads (vmcnt 0)
        if (kk + 1 < kiters) stage(kk + 1, (kk + 1) & 1);  // prefetch overlaps MFMA below
        int p = kk & 1;
        v8s af[4], bf[4];
        #pragma unroll
        for (int mt = 0; mt < 4; mt++)
            af[mt] = *(const v8s*)&As[p][(wm * 64 + mt * 16 + l16) * 32 + quad * 8];
        #pragma unroll
        for (int nt = 0; nt < 4; nt++)
            bf[nt] = *(const v8s*)&Bs[p][(wn * 64 + nt * 16 + l16) * 32 + quad * 8];
        #pragma unroll
        for (int mt = 0; mt < 4; mt++)
            #pragma unroll
            for (int nt = 0; nt < 4; nt++)
                acc[mt][nt] = __builtin_amdgcn_mfma_f32_16x16x32_bf16(
                    af[mt], bf[nt], acc[mt][nt], 0, 0, 0);
    }
}

// ---------------- fused keys-GEMM (+norm) and queries-GEMM (+norm+weight) ----------------
__global__ __launch_bounds__(256) void fused_gemms(const unsigned short* __restrict__ poolb,
                                                   const unsigned short* __restrict__ wtb,
                                                   const unsigned short* __restrict__ zb,
                                                   const unsigned short* __restrict__ wqt,
                                                   const float* __restrict__ logits,
                                                   float* __restrict__ keys_out,
                                                   unsigned short* __restrict__ kb,
                                                   unsigned short* __restrict__ qwb) {
    __shared__ unsigned short As[2][4096], Bs[2][4096];
    v4f acc[4][4];
    #pragma unroll
    for (int mt = 0; mt < 4; mt++)
        #pragma unroll
        for (int nt = 0; nt < 4; nt++) acc[mt][nt] = (v4f)(0.f);

    int blk = blockIdx.x;
    bool is_q = blk >= 256;
    const unsigned short* A;
    const unsigned short* Bm;
    int lda, mbase, nbase, kiters;
    if (is_q) {
        int q = blk - 256;
        A = zb; Bm = wqt; lda = DA_DIM; kiters = DA_DIM / 32;
        mbase = (q >> 2) * 128; nbase = (q & 3) * 128;
    } else {
        A = poolb; Bm = wtb; lda = D_DIM; kiters = D_DIM / 32;
        mbase = (blk >> 2) * 128; nbase = (blk & 3) * 128;
    }

    gemm_mainloop(A, lda, Bm, lda, mbase, nbase, kiters, As, Bs, acc);

    int tid = threadIdx.x, wid = tid >> 6, lane = tid & 63;
    int wm = wid >> 1, wn = wid & 1, quad = lane >> 4, l16 = lane & 15;

    if (is_q) {
        float l[8]; float mx = -1e30f;
        #pragma unroll
        for (int i = 0; i < 8; i++) { l[i] = logits[i]; mx = fmaxf(mx, l[i]); }
        float se = 0.f;
        #pragma unroll
        for (int i = 0; i < 8; i++) { l[i] = __expf(l[i] - mx); se += l[i]; }
        float wa = l[(nbase >> 6) + wn] / se;

        #pragma unroll
        for (int mt = 0; mt < 4; mt++)
            #pragma unroll
            for (int r = 0; r < 4; r++) {
                float ss = 0.f;
                #pragma unroll
                for (int nt = 0; nt < 4; nt++) ss += acc[mt][nt][r] * acc[mt][nt][r];
                ss += __shfl_xor(ss, 1, 64);
                ss += __shfl_xor(ss, 2, 64);
                ss += __shfl_xor(ss, 4, 64);
                ss += __shfl_xor(ss, 8, 64);
                float sc = wa / (sqrtf(ss) + 1e-8f);
                int row = mbase + wm * 64 + mt * 16 + quad * 4 + r;
                #pragma unroll
                for (int nt = 0; nt < 4; nt++) {
                    int col = nbase + wn * 64 + nt * 16 + l16;
                    qwb[(size_t)row * C_DIM + col] =
                        (unsigned short)f2bf(acc[mt][nt][r] * sc);
                }
            }
    } else {
        #pragma unroll
        for (int mt = 0; mt < 4; mt++)
            #pragma unroll
            for (int r = 0; r < 4; r++) {
                float ss = 0.f;
                #pragma unroll
                for (int nt = 0; nt < 4; nt++) ss += acc[mt][nt][r] * acc[mt][nt][r];
                ss += __shfl_xor(ss, 1, 64);
                ss += __shfl_xor(ss, 2, 64);
                ss += __shfl_xor(ss, 4, 64);
                ss += __shfl_xor(ss, 8, 64);
                float sc = 1.0f / (sqrtf(ss) + 1e-8f);
                int row = mbase + wm * 64 + mt * 16 + quad * 4 + r;
                #pragma unroll
                for (int nt = 0; nt < 4; nt++) {
                    int col = nbase + wn * 64 + nt * 16 + l16;
                    float s = acc[mt][nt][r];
                    keys_out[(size_t)row * C_DIM + col] = s;
                    kb[(size_t)row * C_DIM + col] = (unsigned short)f2bf(s * sc);
                }
            }
    }
}

// ---------------- scores = Qw * K^T + epilogue partial row-sums ----------------
__global__ __launch_bounds__(256) void scores_gemm(const unsigned short* __restrict__ qwb,
                                                   const unsigned short* __restrict__ kb,
                                                   float* __restrict__ scores_out,
                                                   float* __restrict__ partials,
                                                   const float* __restrict__ lam_p,
                                                   const float* __restrict__ tau_p,
                                                   const float* __restrict__ temp_p) {
    __shared__ unsigned short As[2][4096], Bs[2][4096];
    __shared__ float rowpart[128];
    v4f acc[4][4];
    #pragma unroll
    for (int mt = 0; mt < 4; mt++)
        #pragma unroll
        for (int nt = 0; nt < 4; nt++) acc[mt][nt] = (v4f)(0.f);

    int mbase = blockIdx.y * 128, nbase = blockIdx.x * 128;
    gemm_mainloop(qwb, C_DIM, kb, C_DIM, mbase, nbase, C_DIM / 32, As, Bs, acc);

    int tid = threadIdx.x, wid = tid >> 6, lane = tid & 63;
    int wm = wid >> 1, wn = wid & 1, quad = lane >> 4, l16 = lane & 15;

    if (tid < 128) rowpart[tid] = 0.f;
    __syncthreads();

    float lam = lam_p[0], tau = tau_p[0], invT = 1.0f / temp_p[0];
    float rsum[4][4];
    #pragma unroll
    for (int mt = 0; mt < 4; mt++)
        #pragma unroll
        for (int r = 0; r < 4; r++) rsum[mt][r] = 0.f;

    #pragma unroll
    for (int mt = 0; mt < 4; mt++)
        #pragma unroll
        for (int nt = 0; nt < 4; nt++)
            #pragma unroll
            for (int r = 0; r < 4; r++) {
                float s = acc[mt][nt][r];
                int row = mbase + wm * 64 + mt * 16 + quad * 4 + r;
                int col = nbase + wn * 64 + nt * 16 + l16;
                scores_out[(size_t)row * N_DIM + col] = s;
                float g = 1.0f / (1.0f + __expf(-lam * (s - tau)));
                rsum[mt][r] += g * __expf(s * invT);
            }
    #pragma unroll
    for (int mt = 0; mt < 4; mt++)
        #pragma unroll
        for (int r = 0; r < 4; r++) {
            float v = rsum[mt][r];
            v += __shfl_xor(v, 1, 64);
            v += __shfl_xor(v, 2, 64);
            v += __shfl_xor(v, 4, 64);
            v += __shfl_xor(v, 8, 64);
            if (l16 == 0)
                atomicAdd(&rowpart[wm * 64 + mt * 16 + quad * 4 + r], v);
        }
    __syncthreads();
    if (tid < 128)
        partials[(size_t)blockIdx.x * B_DIM + mbase + tid] = rowpart[tid];
}

// ---------------- alpha = g*exp(s/T) / rowsum (partials reduced in-kernel) ----------------
__global__ __launch_bounds__(256) void alpha_kernel(const float* __restrict__ scores,
                                                    const float* __restrict__ partials,
                                                    float* __restrict__ alpha,
                                                    const float* __restrict__ lam_p,
                                                    const float* __restrict__ tau_p,
                                                    const float* __restrict__ temp_p) {
    __shared__ float s_inv;
    int b = blockIdx.x;                       // one row per block, 512 blocks
    int tid = threadIdx.x;
    if (tid < 64) {
        float v = partials[(size_t)tid * B_DIM + b];
        v += __shfl_xor(v, 1, 64);
        v += __shfl_xor(v, 2, 64);
        v += __shfl_xor(v, 4, 64);
        v += __shfl_xor(v, 8, 64);
        v += __shfl_xor(v, 16, 64);
        v += __shfl_xor(v, 32, 64);
        if (tid == 0) s_inv = 1.0f / (v + 1e-8f);
    }
    __syncthreads();
    float inv = s_inv;
    float lam = lam_p[0], tau = tau_p[0], invT = 1.0f / temp_p[0];
    const float4* srow = (const float4*)(scores + (size_t)b * N_DIM);
    float4* arow = (float4*)(alpha + (size_t)b * N_DIM);
    #pragma unroll
    for (int i = 0; i < 8; i++) {
        int idx = tid + i * 256;              // 0..2047 float4
        float4 s4 = srow[idx];
        float4 o;
        o.x = (1.0f / (1.0f + __expf(-lam * (s4.x - tau)))) * __expf(s4.x * invT) * inv;
        o.y = (1.0f / (1.0f + __expf(-lam * (s4.y - tau)))) * __expf(s4.y * invT) * inv;
        o.z = (1.0f / (1.0f + __expf(-lam * (s4.z - tau)))) * __expf(s4.z * invT) * inv;
        o.w = (1.0f / (1.0f + __expf(-lam * (s4.w - tau)))) * __expf(s4.w * invT) * inv;
        arow[idx] = o;
    }
}

extern "C" void kernel_launch(void* const* d_in, const int* in_sizes, int n_in,
                              void* d_out, int out_size, void* d_ws, size_t ws_size,
                              hipStream_t stream) {
    const float* z      = (const float*)d_in[0];
    const float* pool   = (const float*)d_in[1];
    const float* W_Q    = (const float*)d_in[2];
    const float* W_K    = (const float*)d_in[3];
    const float* logits = (const float*)d_in[4];
    const float* tau    = (const float*)d_in[5];
    const float* lam    = (const float*)d_in[6];
    const float* temp   = (const float*)d_in[7];

    float* alpha  = (float*)d_out;
    float* scores = alpha + (size_t)B_DIM * N_DIM;
    float* keys   = scores + (size_t)B_DIM * N_DIM;

    char* ws = (char*)d_ws;
    unsigned short* poolb = (unsigned short*)(ws);             // 16,777,216 B
    unsigned short* kb    = (unsigned short*)(ws + 16777216);  //  8,388,608 B
    unsigned short* wtb   = (unsigned short*)(ws + 25165824);  //  1,048,576 B
    unsigned short* wqt   = (unsigned short*)(ws + 26214400);  //    524,288 B
    unsigned short* zb    = (unsigned short*)(ws + 26738688);  //    524,288 B
    unsigned short* qwb   = (unsigned short*)(ws + 27262976);  //    524,288 B
    float* partials       = (float*)(ws + 27787264);           //    131,072 B

    prep<<<dim3(4416), dim3(256), 0, stream>>>(pool, z, W_Q, W_K,
                                               poolb, zb, wqt, wtb);
    fused_gemms<<<dim3(272), dim3(256), 0, stream>>>(poolb, wtb, zb, wqt, logits,
                                                     keys, kb, qwb);
    scores_gemm<<<dim3(64, 4), dim3(256), 0, stream>>>(qwb, kb, scores, partials,
                                                       lam, tau, temp);
    alpha_kernel<<<dim3(512), dim3(256), 0, stream>>>(scores, partials, alpha,
                                                      lam, tau, temp);
}